// Round 2
// baseline (381.883 us; speedup 1.0000x reference)
//
#include <hip/hip_runtime.h>
#include <stdint.h>

// out[b,d,m] = (sum_n seg[b,d,n]*Wt[b,m,n]) / (sum_n Wt[b,m,n]),  Wt = W*(W>0.85)
// bs=4, d=16, n=4096. W = 268 MB read once -> memory floor ~43 us kernel.
//
// R6: counted-vmcnt, occupancy-preserving. R5's 4x16KB LDS (64 KB) capped
// residency at 2 blocks/CU (vs 3 VGPR-capped for R4's 32 KB) and regressed
// +21 us: wave count, not prefetch depth, was the scarce resource.
// R6: 2 LDS buffers (32 KB, seg depth-1, staged at phase top into the
// buffer last read one barrier ago) + W depth-2 in REGISTERS (no LDS cost).
// Ledger: phase c outstanding at wait = [st(c)x4 | W(c+1)x4] -> vmcnt(4)
// retires the seg stage while next W chunk stays in flight across the
// barrier. vmcnt(8) at phase 0 (prologue = st0+W0+W1), vmcnt(0) at last.
// STAGE pinned before LOADW by a mem clobber (asymmetric depths make the
// ledger order-sensitive). One barrier per chunk, same as R4. Numerics
// bit-identical to R4/R5.

typedef float v4f __attribute__((ext_vector_type(4)));

#define N_DIM 4096
#define D_DIM 16
#define THRESH 0.85f
#define RPW 4                  // rows per wave; block = 4 waves = 16 rows
#define CHUNK 256              // n per chunk (64 lanes x float4)
#define NCHUNK (N_DIM / CHUNK) // 16

__global__ __launch_bounds__(256) void regu_kernel(
    const float* __restrict__ seg,   // [4][16][4096]
    const float* __restrict__ W,     // [4][4096][4096]
    float* __restrict__ out)         // [4][16][4096]
{
    __shared__ float stile[2][D_DIM * CHUNK];   // 2 x 16 KB seg tiles = 32 KB

    const int lane = threadIdx.x & 63;
    const int wv   = threadIdx.x >> 6;
    const int row0 = blockIdx.x * 16 + wv * RPW;   // [0, 16384)
    const int b  = row0 >> 12;
    const int m0 = row0 & (N_DIM - 1);

    const float* Wp   = W   + ((size_t)b * N_DIM + m0) * N_DIM + lane * 4;
    const float* segb = seg + (size_t)b * D_DIM * N_DIM;

    float acc[RPW * D_DIM];                 // acc[r*16+d]
    float rowsum[RPW] = {0.f, 0.f, 0.f, 0.f};
#pragma unroll
    for (int i = 0; i < RPW * D_DIM; ++i) acc[i] = 0.f;

    // stage chunk c of seg (16 rows x 1 KB) into stile[sb]; wave wv stages
    // rows wv*4..wv*4+3. LDS dest is wave-uniform row base (HW adds lane*16).
    // 4 vmem ops per wave per chunk.
#define STAGE(c, sb)                                                          \
    do {                                                                      \
        _Pragma("unroll")                                                     \
        for (int j = 0; j < 4; ++j) {                                         \
            const int d_ = wv * 4 + j;                                        \
            const float* g_ = segb + (size_t)d_ * N_DIM + (size_t)(c) * CHUNK + lane * 4; \
            __builtin_amdgcn_global_load_lds(                                 \
                (const __attribute__((address_space(1))) uint32_t*)g_,        \
                (__attribute__((address_space(3))) uint32_t*)&stile[sb][d_ * CHUNK], \
                16, 0, 0);                                                    \
        }                                                                     \
    } while (0)

    // 4 vmem ops per wave per chunk (one dwordx4 per row)
#define LOADW(dst, c)                                                         \
    do {                                                                      \
        const float* p_ = Wp + (size_t)(c) * CHUNK;                           \
        _Pragma("unroll")                                                     \
        for (int r = 0; r < RPW; ++r)                                         \
            dst[r] = __builtin_nontemporal_load(                              \
                (const v4f*)(p_ + (size_t)r * N_DIM));                        \
    } while (0)

    v4f wR0[RPW], wR1[RPW];   // two named W reg sets (even/odd chunks)

    // one chunk: threshold W regs, rowsum, FMA against LDS seg tile.
    // sb is a literal at every call site -> addresses fold at compile time.
    auto compute = [&](const v4f (&w_in)[RPW], const int sb) {
        v4f w[RPW];
#pragma unroll
        for (int r = 0; r < RPW; ++r) {
            v4f v = w_in[r];
            v.x = (v.x > THRESH) ? v.x : 0.f;
            v.y = (v.y > THRESH) ? v.y : 0.f;
            v.z = (v.z > THRESH) ? v.z : 0.f;
            v.w = (v.w > THRESH) ? v.w : 0.f;
            w[r] = v;
            rowsum[r] += (v.x + v.y) + (v.z + v.w);
        }
#pragma unroll
        for (int d = 0; d < D_DIM; ++d) {
            const v4f s = *(const v4f*)&stile[sb][d * CHUNK + lane * 4];
#pragma unroll
            for (int r = 0; r < RPW; ++r) {
                acc[r * D_DIM + d] += w[r].x * s.x;
                acc[r * D_DIM + d] += w[r].y * s.y;
                acc[r * D_DIM + d] += w[r].z * s.z;
                acc[r * D_DIM + d] += w[r].w * s.w;
            }
        }
    };

    // prologue: seg chunk 0 staged; W chunks 0,1 in registers.
    // Outstanding (oldest->newest): st0[4], W0[4], W1[4] = 12.
    STAGE(0, 0);
    asm volatile("" ::: "memory");   // pin st0 oldest
    LOADW(wR0, 0);
    LOADW(wR1, 1);
    asm volatile("" ::: "memory");

    // Phase c: wait until seg stage(c) retired (vmcnt leaves W(c+1) in
    // flight); barrier publishes all waves' stages of chunk c AND ensures
    // buffer (c+1)&1 (read at phase c-1) is free; stage chunk c+1 into it;
    // compute chunk c; refill this W reg set with chunk c+2. Main loop
    // never drains vmcnt to 0.
#define PHASE_BODY(c_, WSET, SB)                                       \
    do {                                                               \
        if (c_ == 0)                                                   \
            asm volatile("s_waitcnt vmcnt(8)" ::: "memory");           \
        else if (c_ < NCHUNK - 1)                                      \
            asm volatile("s_waitcnt vmcnt(4)" ::: "memory");           \
        else                                                           \
            asm volatile("s_waitcnt vmcnt(0)" ::: "memory");           \
        __builtin_amdgcn_s_barrier();                                  \
        if (c_ + 1 < NCHUNK) STAGE(c_ + 1, (SB) ^ 1);                  \
        asm volatile("" ::: "memory");  /* STAGE issues before LOADW */ \
        compute(WSET, SB);                                             \
        if (c_ + 2 < NCHUNK) LOADW(WSET, c_ + 2);                      \
    } while (0)

    for (int cc = 0; cc < NCHUNK; cc += 2) {
        PHASE_BODY(cc,     wR0, 0);
        PHASE_BODY(cc + 1, wR1, 1);
    }

#undef PHASE_BODY
#undef LOADW
#undef STAGE

    // scatter-reduce 64 partials: after 6 steps lane l holds the total for
    // index j = bitrev6(l)  (verified numerically in R2/R3)
#pragma unroll
    for (int k = 0; k < 6; ++k) {
        const int S = 32 >> k;
        const bool up = (lane >> k) & 1;
#pragma unroll
        for (int j = 0; j < S; ++j) {
            const float mine = up ? acc[j + S] : acc[j];
            const float send = up ? acc[j] : acc[j + S];
            acc[j] = mine + __shfl_xor(send, 1 << k, 64);
        }
    }

#pragma unroll
    for (int r = 0; r < RPW; ++r) {
        float s = rowsum[r];
#pragma unroll
        for (int off = 1; off < 64; off <<= 1) s += __shfl_xor(s, off, 64);
        rowsum[r] = s;
    }

    const int j = __brev((unsigned)lane) >> 26;   // bitrev6
    const int r = j >> 4;
    const int d = j & 15;
    const float inv = 1.0f / (r < 2 ? (r == 0 ? rowsum[0] : rowsum[1])
                                    : (r == 2 ? rowsum[2] : rowsum[3]));
    out[((size_t)b * D_DIM + d) * N_DIM + (m0 + r)] = acc[0] * inv;
}

extern "C" void kernel_launch(void* const* d_in, const int* in_sizes, int n_in,
                              void* d_out, int out_size, void* d_ws, size_t ws_size,
                              hipStream_t stream) {
    const float* seg = (const float*)d_in[0];   // [4,16,64,64] fp32
    const float* W   = (const float*)d_in[1];   // [4,4096,4096] fp32
    float* out = (float*)d_out;                 // [4,16,64,64] fp32

    // 16384 rows / (4 waves x 4 rows) = 1024 blocks
    regu_kernel<<<1024, 256, 0, stream>>>(seg, W, out);
}

// Round 3
// 373.698 us; speedup vs baseline: 1.0219x; 1.0219x over previous
//
#include <hip/hip_runtime.h>
#include <stdint.h>

// out[b,d,m] = (sum_n seg[b,d,n]*Wt[b,m,n]) / (sum_n Wt[b,m,n]),  Wt = W*(W>0.85)
// bs=4, d=16, n=4096. W = 268 MB read once -> memory floor ~43 us kernel.
//
// R7: barrier-free, LDS-free. R5/R6 (manual counted-vmcnt + mem-clobber asm)
// both regressed vs R4 -> hand-managing the queue defeats the compiler
// (m141 lesson). R4's real costs: __syncthreads every 1KB of W drains the
// c+1 prefetch (vmcnt(0)) and lockstep-couples 4 waves. The pre-LDS
// entanglement stall (R3) has a pure SOURCE-ORDER fix instead: issue seg(c)
// loads BEFORE the W(c+1) prefetch, so the in-order VMEM queue is
// [seg(c).., W(c+1)..] and the compiler's own counted wait for seg(c)
// (vmcnt(4)) leaves W(c+1) in flight. One sched_barrier(0) per chunk pins
// that boundary (scheduling-only fence, not a memory clobber). seg now read
// per-wave (4x amplification) but is 1 MB / L1+L2-resident: ~30 us of
// fully-overlapped L2 time. No LDS -> no occupancy coupling; waves
// free-run. Numerics bit-identical to R4 (same n-order per (d,m)).

typedef float v4f __attribute__((ext_vector_type(4)));

#define N_DIM 4096
#define D_DIM 16
#define THRESH 0.85f
#define RPW 4                  // rows per wave; block = 4 waves = 16 rows
#define CHUNK 256              // n per chunk (64 lanes x float4)
#define NCHUNK (N_DIM / CHUNK) // 16

__global__ __launch_bounds__(256) void regu_kernel(
    const float* __restrict__ seg,   // [4][16][4096]
    const float* __restrict__ W,     // [4][4096][4096]
    float* __restrict__ out)         // [4][16][4096]
{
    const int lane = threadIdx.x & 63;
    const int wv   = threadIdx.x >> 6;
    const int row0 = blockIdx.x * 16 + wv * RPW;   // [0, 16384)
    const int b  = row0 >> 12;
    const int m0 = row0 & (N_DIM - 1);

    const float* Wp   = W   + ((size_t)b * N_DIM + m0) * N_DIM + lane * 4;
    const float* segp = seg + (size_t)b * D_DIM * N_DIM + lane * 4;

    float acc[RPW * D_DIM];                 // acc[r*16+d]
    float rowsum[RPW] = {0.f, 0.f, 0.f, 0.f};
#pragma unroll
    for (int i = 0; i < RPW * D_DIM; ++i) acc[i] = 0.f;

    // 4 vmem ops (one dwordx4 per row), nontemporal: W is stream-once
#define LOADW(dst, c)                                                         \
    do {                                                                      \
        const float* p_ = Wp + (size_t)(c) * CHUNK;                           \
        _Pragma("unroll")                                                     \
        for (int r = 0; r < RPW; ++r)                                         \
            dst[r] = __builtin_nontemporal_load(                              \
                (const v4f*)(p_ + (size_t)r * N_DIM));                        \
    } while (0)

    // 16 vmem ops; L1/L2 hits (seg = 1 MB resident). Plain loads (cached).
#define SEGLOAD(s_, c)                                                        \
    do {                                                                      \
        _Pragma("unroll")                                                     \
        for (int d = 0; d < D_DIM; ++d)                                       \
            s_[d] = *(const v4f*)(segp + (size_t)d * N_DIM + (size_t)(c) * CHUNK); \
    } while (0)

    // threshold W regs, rowsum, FMA against seg regs (same order as R4)
#define FMA_CHUNK(win, s_)                                                    \
    do {                                                                      \
        v4f w_[RPW];                                                          \
        _Pragma("unroll")                                                     \
        for (int r = 0; r < RPW; ++r) {                                       \
            v4f v = win[r];                                                   \
            v.x = (v.x > THRESH) ? v.x : 0.f;                                 \
            v.y = (v.y > THRESH) ? v.y : 0.f;                                 \
            v.z = (v.z > THRESH) ? v.z : 0.f;                                 \
            v.w = (v.w > THRESH) ? v.w : 0.f;                                 \
            w_[r] = v;                                                        \
            rowsum[r] += (v.x + v.y) + (v.z + v.w);                           \
        }                                                                     \
        _Pragma("unroll")                                                     \
        for (int d = 0; d < D_DIM; ++d) {                                     \
            const v4f sv = s_[d];                                             \
            _Pragma("unroll")                                                 \
            for (int r = 0; r < RPW; ++r) {                                   \
                acc[r * D_DIM + d] += w_[r].x * sv.x;                         \
                acc[r * D_DIM + d] += w_[r].y * sv.y;                         \
                acc[r * D_DIM + d] += w_[r].z * sv.z;                         \
                acc[r * D_DIM + d] += w_[r].w * sv.w;                         \
            }                                                                 \
        }                                                                     \
    } while (0)

    v4f wA[RPW], wB[RPW];
    LOADW(wA, 0);   // prologue: W chunk 0 in flight

    for (int cc = 0; cc < NCHUNK; cc += 2) {
        {   // even chunk cc: seg first, THEN next-W prefetch (queue order!)
            v4f s[D_DIM];
            SEGLOAD(s, cc);
            __builtin_amdgcn_sched_barrier(0);   // keep seg older than W(c+1)
            LOADW(wB, cc + 1);                   // cc+1 <= 15 always
            FMA_CHUNK(wA, s);
        }
        {   // odd chunk cc+1
            v4f s[D_DIM];
            SEGLOAD(s, cc + 1);
            __builtin_amdgcn_sched_barrier(0);
            if (cc + 2 < NCHUNK) LOADW(wA, cc + 2);
            FMA_CHUNK(wB, s);
        }
    }

#undef FMA_CHUNK
#undef SEGLOAD
#undef LOADW

    // scatter-reduce 64 partials: after 6 steps lane l holds the total for
    // index j = bitrev6(l)  (verified numerically in R2/R3)
#pragma unroll
    for (int k = 0; k < 6; ++k) {
        const int S = 32 >> k;
        const bool up = (lane >> k) & 1;
#pragma unroll
        for (int j = 0; j < S; ++j) {
            const float mine = up ? acc[j + S] : acc[j];
            const float send = up ? acc[j] : acc[j + S];
            acc[j] = mine + __shfl_xor(send, 1 << k, 64);
        }
    }

#pragma unroll
    for (int r = 0; r < RPW; ++r) {
        float s = rowsum[r];
#pragma unroll
        for (int off = 1; off < 64; off <<= 1) s += __shfl_xor(s, off, 64);
        rowsum[r] = s;
    }

    const int j = __brev((unsigned)lane) >> 26;   // bitrev6
    const int r = j >> 4;
    const int d = j & 15;
    const float inv = 1.0f / (r < 2 ? (r == 0 ? rowsum[0] : rowsum[1])
                                    : (r == 2 ? rowsum[2] : rowsum[3]));
    out[((size_t)b * D_DIM + d) * N_DIM + (m0 + r)] = acc[0] * inv;
}

extern "C" void kernel_launch(void* const* d_in, const int* in_sizes, int n_in,
                              void* d_out, int out_size, void* d_ws, size_t ws_size,
                              hipStream_t stream) {
    const float* seg = (const float*)d_in[0];   // [4,16,64,64] fp32
    const float* W   = (const float*)d_in[1];   // [4,4096,4096] fp32
    float* out = (float*)d_out;                 // [4,16,64,64] fp32

    // 16384 rows / (4 waves x 4 rows) = 1024 blocks
    regu_kernel<<<1024, 256, 0, stream>>>(seg, W, out);
}

// Round 4
// 355.328 us; speedup vs baseline: 1.0747x; 1.0517x over previous
//
#include <hip/hip_runtime.h>
#include <stdint.h>

// out[b,d,m] = (sum_n seg[b,d,n]*Wt[b,m,n]) / (sum_n Wt[b,m,n]),  Wt = W*(W>0.85)
// bs=4, d=16, n=4096. W = 268 MB read once -> memory floor ~40 us kernel.
//
// R8 = R4 reverted (best: 354.3/355.1 us total). Session evidence that R4 is
// AT the HBM roofline:
//  - rocprof top-5 are all ~160 us harness poison fills at 82-84% HBM peak;
//    regu_kernel is below the 160 us cutoff -> kernel residual ~35-45 us vs
//    the 268MB/6.7TB/s = 40 us mandatory-traffic floor.
//  - Three structurally disjoint rewrites all regressed consistently:
//    R5 counted-vmcnt + 4xLDS (376, occupancy 3->2 blocks/CU),
//    R6 counted-vmcnt + W-in-regs (382, clobber fences defeat scheduler),
//    R7 barrier-free no-LDS source-ordered (374, 4x seg L1 amplification).
//  - m114 lesson confirmed: at 3 blocks/CU the inter-block wave overlap
//    already hides the per-chunk __syncthreads vmcnt drain; explicit
//    pipelining only added costs.
// Structure: seg staged in LDS (double-buffered, global_load_lds w=16) so the
// seg stream rides lgkmcnt, decoupled from the W vmcnt stream. RPW=4
// (RPW=2 doubles seg amplification; regressed in the prior session).
// W loads nontemporal (stream-once).

typedef float v4f __attribute__((ext_vector_type(4)));

#define N_DIM 4096
#define D_DIM 16
#define THRESH 0.85f
#define RPW 4                  // rows per wave; block = 4 waves = 16 rows
#define CHUNK 256              // n per chunk (64 lanes x float4)
#define NCHUNK (N_DIM / CHUNK) // 16

__global__ __launch_bounds__(256) void regu_kernel(
    const float* __restrict__ seg,   // [4][16][4096]
    const float* __restrict__ W,     // [4][4096][4096]
    float* __restrict__ out)         // [4][16][4096]
{
    __shared__ float stile[2][D_DIM * CHUNK];   // 2 x 16 KB seg tiles

    const int lane = threadIdx.x & 63;
    const int wv   = threadIdx.x >> 6;
    const int row0 = blockIdx.x * 16 + wv * RPW;   // [0, 16384)
    const int b  = row0 >> 12;
    const int m0 = row0 & (N_DIM - 1);

    const float* Wp   = W   + ((size_t)b * N_DIM + m0) * N_DIM + lane * 4;
    const float* segb = seg + (size_t)b * D_DIM * N_DIM;

    float acc[RPW * D_DIM];                 // acc[r*16+d]
    float rowsum[RPW] = {0.f, 0.f, 0.f, 0.f};
#pragma unroll
    for (int i = 0; i < RPW * D_DIM; ++i) acc[i] = 0.f;

    // stage chunk c of seg (16 rows x 1 KB) into stile[sb]; wave wv does rows
    // wv*4..wv*4+3. LDS dest is the wave-uniform row base (HW adds lane*16).
#define STAGE(c, sb)                                                          \
    do {                                                                      \
        _Pragma("unroll")                                                     \
        for (int j = 0; j < 4; ++j) {                                         \
            const int d_ = wv * 4 + j;                                        \
            const float* g_ = segb + (size_t)d_ * N_DIM + (c) * CHUNK + lane * 4; \
            __builtin_amdgcn_global_load_lds(                                 \
                (const __attribute__((address_space(1))) uint32_t*)g_,        \
                (__attribute__((address_space(3))) uint32_t*)&stile[sb][d_ * CHUNK], \
                16, 0, 0);                                                    \
        }                                                                     \
    } while (0)

    v4f wA[RPW], wB[RPW];

    // prologue: stage seg chunk 0, load W chunk 0
    STAGE(0, 0);
#pragma unroll
    for (int r = 0; r < RPW; ++r)
        wA[r] = __builtin_nontemporal_load((const v4f*)(Wp + (size_t)r * N_DIM));
    __syncthreads();   // drains vmcnt: tile0 + wA ready

    // one chunk: threshold W regs, rowsum, FMA against LDS seg tile
    auto compute = [&](const v4f* w_in, int sb) {
        v4f w[RPW];
#pragma unroll
        for (int r = 0; r < RPW; ++r) {
            v4f v = w_in[r];
            v.x = (v.x > THRESH) ? v.x : 0.f;
            v.y = (v.y > THRESH) ? v.y : 0.f;
            v.z = (v.z > THRESH) ? v.z : 0.f;
            v.w = (v.w > THRESH) ? v.w : 0.f;
            w[r] = v;
            rowsum[r] += (v.x + v.y) + (v.z + v.w);
        }
#pragma unroll
        for (int d = 0; d < D_DIM; ++d) {
            const v4f s = *(const v4f*)&stile[sb][d * CHUNK + lane * 4];
#pragma unroll
            for (int r = 0; r < RPW; ++r) {
                acc[r * D_DIM + d] += w[r].x * s.x;
                acc[r * D_DIM + d] += w[r].y * s.y;
                acc[r * D_DIM + d] += w[r].z * s.z;
                acc[r * D_DIM + d] += w[r].w * s.w;
            }
        }
    };

    for (int c = 0; c < NCHUNK; c += 2) {
        // iter c (even): compute from stile[0]/wA; stage c+1 -> stile[1]/wB
        STAGE(c + 1, 1);
        {
            const float* p = Wp + (size_t)(c + 1) * CHUNK;
#pragma unroll
            for (int r = 0; r < RPW; ++r)
                wB[r] = __builtin_nontemporal_load((const v4f*)(p + (size_t)r * N_DIM));
        }
        compute(wA, 0);
        __syncthreads();   // tile1/wB ready; everyone done reading tile0

        // iter c+1 (odd): compute from stile[1]/wB; stage c+2 -> stile[0]/wA
        if (c + 2 < NCHUNK) {
            STAGE(c + 2, 0);
            const float* p = Wp + (size_t)(c + 2) * CHUNK;
#pragma unroll
            for (int r = 0; r < RPW; ++r)
                wA[r] = __builtin_nontemporal_load((const v4f*)(p + (size_t)r * N_DIM));
        }
        compute(wB, 1);
        __syncthreads();
    }

    // scatter-reduce 64 partials: after 6 steps lane l holds the total for
    // index j = bitrev6(l)  (verified numerically in R2/R3)
#pragma unroll
    for (int k = 0; k < 6; ++k) {
        const int S = 32 >> k;
        const bool up = (lane >> k) & 1;
#pragma unroll
        for (int j = 0; j < S; ++j) {
            const float mine = up ? acc[j + S] : acc[j];
            const float send = up ? acc[j] : acc[j + S];
            acc[j] = mine + __shfl_xor(send, 1 << k, 64);
        }
    }

#pragma unroll
    for (int r = 0; r < RPW; ++r) {
        float s = rowsum[r];
#pragma unroll
        for (int off = 1; off < 64; off <<= 1) s += __shfl_xor(s, off, 64);
        rowsum[r] = s;
    }

    const int j = __brev((unsigned)lane) >> 26;   // bitrev6
    const int r = j >> 4;
    const int d = j & 15;
    const float inv = 1.0f / (r < 2 ? (r == 0 ? rowsum[0] : rowsum[1])
                                    : (r == 2 ? rowsum[2] : rowsum[3]));
    out[((size_t)b * D_DIM + d) * N_DIM + (m0 + r)] = acc[0] * inv;
}

extern "C" void kernel_launch(void* const* d_in, const int* in_sizes, int n_in,
                              void* d_out, int out_size, void* d_ws, size_t ws_size,
                              hipStream_t stream) {
    const float* seg = (const float*)d_in[0];   // [4,16,64,64] fp32
    const float* W   = (const float*)d_in[1];   // [4,4096,4096] fp32
    float* out = (float*)d_out;                 // [4,16,64,64] fp32

    // 16384 rows / (4 waves x 4 rows) = 1024 blocks
    regu_kernel<<<1024, 256, 0, stream>>>(seg, W, out);
}